// Round 1
// baseline (739.388 us; speedup 1.0000x reference)
//
#include <hip/hip_runtime.h>

// Matrix-factorization forward:
//   pred[b] = sum_h (uw[u][h] + ub[u]) * (iw[i][h] + ib[i]) + bias[0]
// B = 1,048,576, H = 64 (256 B rows).
//
// v2: bucket-locality pipeline. The direct kernel is floored at ~1.07 TB/s
// effective because BOTH gather streams are fully random 256 B accesses
// (DRAM row-activate limited; fills on the same chip stream at 6.7 TB/s).
// We reorder the batch by user-index bucket (1024 buckets = 256 KB table
// windows) so the user-side gathers get DRAM row-buffer + L2 locality and
// duplicate rows (~37% of accesses) become cache hits. Item side remains
// random. Pipeline: zero -> histogram -> scan -> scatter -> compute.
// Falls back to the direct kernel if the workspace is too small.

#define NBUCKET 1024
#define BSHIFT  10   // bucket = user >> 10  (1024 rows = 256 KB window)

// ---------------- K0: zero bucket counters ----------------
__global__ __launch_bounds__(1024) void mf_zero(int* __restrict__ counts)
{
    counts[threadIdx.x] = 0;
}

// ---------------- K1: histogram of user-index buckets ----------------
__global__ __launch_bounds__(1024) void mf_hist(const int* __restrict__ user,
                                                int batch,
                                                int* __restrict__ counts)
{
    __shared__ int lc[NBUCKET];
    for (int i = threadIdx.x; i < NBUCKET; i += blockDim.x) lc[i] = 0;
    __syncthreads();
    for (int i = blockIdx.x * blockDim.x + threadIdx.x; i < batch;
         i += gridDim.x * blockDim.x)
        atomicAdd(&lc[user[i] >> BSHIFT], 1);
    __syncthreads();
    for (int i = threadIdx.x; i < NBUCKET; i += blockDim.x) {
        const int c = lc[i];
        if (c) atomicAdd(&counts[i], c);
    }
}

// ---------------- K2: exclusive scan (one block, 1024 threads) ----------------
__global__ __launch_bounds__(1024) void mf_scan(const int* __restrict__ counts,
                                                int* __restrict__ offsets,
                                                int* __restrict__ cursor)
{
    const int t    = threadIdx.x;
    const int lane = t & 63;
    const int wid  = t >> 6;

    const int v = counts[t];
    int x = v;
    #pragma unroll
    for (int off = 1; off < 64; off <<= 1) {
        const int y = __shfl_up(x, off, 64);
        if (lane >= off) x += y;
    }
    __shared__ int wsum[16], wpre[16];
    if (lane == 63) wsum[wid] = x;
    __syncthreads();
    if (t == 0) {
        int s = 0;
        for (int w = 0; w < 16; ++w) { wpre[w] = s; s += wsum[w]; }
    }
    __syncthreads();
    const int excl = x - v + wpre[wid];
    offsets[t] = excl;
    cursor[t]  = excl;
    if (t == NBUCKET - 1) offsets[NBUCKET] = excl + v;
}

// ---------------- K3: scatter samples into bucket order ----------------
__global__ __launch_bounds__(256) void mf_scatter(const int* __restrict__ user,
                                                  const int* __restrict__ item,
                                                  int batch,
                                                  int* __restrict__ cursor,
                                                  int* __restrict__ s_user,
                                                  int* __restrict__ s_item,
                                                  int* __restrict__ s_pos)
{
    for (int i = blockIdx.x * blockDim.x + threadIdx.x; i < batch;
         i += gridDim.x * blockDim.x) {
        const int u  = user[i];
        const int it = item[i];
        const int slot = atomicAdd(&cursor[u >> BSHIFT], 1);
        s_user[slot] = u;
        s_item[slot] = it;
        s_pos[slot]  = i;
    }
}

// ---------------- K4: per-bucket compute ----------------
// Same 16-lanes-per-row / 4-rows-per-thread structure as the proven direct
// kernel; rows now come from the bucket-sorted arrays, so all user gathers
// of a block land in one 256 KB window of user_weight.
__global__ __launch_bounds__(256) void mf_bucket_compute(
    const int*   __restrict__ s_user,
    const int*   __restrict__ s_item,
    const int*   __restrict__ s_pos,
    const int*   __restrict__ offsets,
    const float* __restrict__ user_weight,
    const float* __restrict__ item_weight,
    const float* __restrict__ user_bias,
    const float* __restrict__ item_bias,
    const float* __restrict__ bias,
    float*       __restrict__ out)
{
    const int start = offsets[blockIdx.x];
    const int end   = offsets[blockIdx.x + 1];
    if (start >= end) return;

    const int lane16 = threadIdx.x & 15;
    const int grp    = threadIdx.x >> 4;
    const float b0   = bias[0];

    for (int base = start; base < end; base += 64) {
        int u[4], it[4], pos[4];
        bool ok[4];
        #pragma unroll
        for (int k = 0; k < 4; ++k) {
            const int r  = base + grp + k * 16;   // uniform across the 16 lanes
            ok[k]        = r < end;
            const int rr = ok[k] ? r : start;     // start is valid (start < end)
            u[k]   = s_user[rr];
            it[k]  = s_item[rr];
            pos[k] = s_pos[rr];
        }

        // 8 independent 256 B row gathers in flight per thread.
        float4 uw[4], iw[4];
        #pragma unroll
        for (int k = 0; k < 4; ++k) {
            uw[k] = ((const float4*)(user_weight + (size_t)u[k]  * 64))[lane16];
            iw[k] = ((const float4*)(item_weight + (size_t)it[k] * 64))[lane16];
        }

        float ub[4], ib[4];
        #pragma unroll
        for (int k = 0; k < 4; ++k) {
            ub[k] = user_bias[u[k]];
            ib[k] = item_bias[it[k]];
        }

        float s[4];
        #pragma unroll
        for (int k = 0; k < 4; ++k) {
            s[k] = (uw[k].x + ub[k]) * (iw[k].x + ib[k])
                 + (uw[k].y + ub[k]) * (iw[k].y + ib[k])
                 + (uw[k].z + ub[k]) * (iw[k].z + ib[k])
                 + (uw[k].w + ub[k]) * (iw[k].w + ib[k]);
        }

        #pragma unroll
        for (int off = 8; off >= 1; off >>= 1) {
            #pragma unroll
            for (int k = 0; k < 4; ++k) s[k] += __shfl_xor(s[k], off, 16);
        }

        if (lane16 == 0) {
            #pragma unroll
            for (int k = 0; k < 4; ++k)
                if (ok[k]) out[pos[k]] = s[k] + b0;
        }
    }
}

// ---------------- fallback: proven direct kernel (501 µs) ----------------
__global__ __launch_bounds__(256) void MF_73856257622285_kernel(
    const int*   __restrict__ user,
    const int*   __restrict__ item,
    const float* __restrict__ user_weight,
    const float* __restrict__ item_weight,
    const float* __restrict__ user_bias,
    const float* __restrict__ item_bias,
    const float* __restrict__ bias,
    float*       __restrict__ out,
    int batch)
{
    const int lane16 = threadIdx.x & 15;
    const int grp    = threadIdx.x >> 4;
    const int row0   = blockIdx.x * 64 + grp;

    int u[4], it[4];
    bool ok[4];
    #pragma unroll
    for (int k = 0; k < 4; ++k) {
        const int r = row0 + k * 16;
        ok[k] = r < batch;
        u[k]  = ok[k] ? user[r] : 0;
        it[k] = ok[k] ? item[r] : 0;
    }

    float4 uw[4], iw[4];
    #pragma unroll
    for (int k = 0; k < 4; ++k) {
        uw[k] = ((const float4*)(user_weight + (size_t)u[k]  * 64))[lane16];
        iw[k] = ((const float4*)(item_weight + (size_t)it[k] * 64))[lane16];
    }

    float ub[4], ib[4];
    #pragma unroll
    for (int k = 0; k < 4; ++k) {
        ub[k] = user_bias[u[k]];
        ib[k] = item_bias[it[k]];
    }

    const float b0 = bias[0];

    float s[4];
    #pragma unroll
    for (int k = 0; k < 4; ++k) {
        s[k] = (uw[k].x + ub[k]) * (iw[k].x + ib[k])
             + (uw[k].y + ub[k]) * (iw[k].y + ib[k])
             + (uw[k].z + ub[k]) * (iw[k].z + ib[k])
             + (uw[k].w + ub[k]) * (iw[k].w + ib[k]);
    }

    #pragma unroll
    for (int off = 8; off >= 1; off >>= 1) {
        #pragma unroll
        for (int k = 0; k < 4; ++k) s[k] += __shfl_xor(s[k], off, 16);
    }

    if (lane16 == 0) {
        #pragma unroll
        for (int k = 0; k < 4; ++k) {
            if (ok[k]) __builtin_nontemporal_store(s[k] + b0, &out[row0 + k * 16]);
        }
    }
}

extern "C" void kernel_launch(void* const* d_in, const int* in_sizes, int n_in,
                              void* d_out, int out_size, void* d_ws, size_t ws_size,
                              hipStream_t stream)
{
    (void)n_in; (void)out_size;

    const int*   user        = (const int*)  d_in[0];
    const int*   item        = (const int*)  d_in[1];
    // d_in[2] = target (unused in forward)
    const float* user_weight = (const float*)d_in[3];
    const float* item_weight = (const float*)d_in[4];
    const float* user_bias   = (const float*)d_in[5];
    const float* item_bias   = (const float*)d_in[6];
    const float* bias        = (const float*)d_in[7];
    float*       out         = (float*)d_out;

    const int batch = in_sizes[0];
    if (batch <= 0) return;

    // Workspace layout: counts[NB] | offsets[NB+1] | cursor[NB] | 3 x batch ints
    const size_t need = (size_t)(3 * NBUCKET + 1) * sizeof(int)
                      + (size_t)batch * 3 * sizeof(int);

    if (d_ws != nullptr && ws_size >= need) {
        int* counts  = (int*)d_ws;
        int* offsets = counts  + NBUCKET;
        int* cursor  = offsets + NBUCKET + 1;
        int* s_user  = cursor  + NBUCKET;
        int* s_item  = s_user  + batch;
        int* s_pos   = s_item  + batch;

        mf_zero<<<1, NBUCKET, 0, stream>>>(counts);
        mf_hist<<<64, 1024, 0, stream>>>(user, batch, counts);
        mf_scan<<<1, NBUCKET, 0, stream>>>(counts, offsets, cursor);
        mf_scatter<<<1024, 256, 0, stream>>>(user, item, batch, cursor,
                                             s_user, s_item, s_pos);
        mf_bucket_compute<<<NBUCKET, 256, 0, stream>>>(
            s_user, s_item, s_pos, offsets,
            user_weight, item_weight, user_bias, item_bias, bias, out);
    } else {
        // Fallback: direct kernel (previous session's best, ~501 µs).
        const int threads = 256;
        const int rows_per_block = 64;
        const int blocks = (batch + rows_per_block - 1) / rows_per_block;
        MF_73856257622285_kernel<<<blocks, threads, 0, stream>>>(
            user, item, user_weight, item_weight, user_bias, item_bias, bias,
            out, batch);
    }
}

// Round 2
// 541.787 us; speedup vs baseline: 1.3647x; 1.3647x over previous
//
#include <hip/hip_runtime.h>

// Matrix-factorization forward:
//   pred[b] = sum_h (uw[u][h] + ub[u]) * (iw[i][h] + ib[i]) + bias[0]
// B = 1,048,576, H = 64 (256 B rows).
//
// v3: bucket-locality pipeline with a DETERMINISTIC two-level counting sort.
// Round-1 post-mortem: the atomic scatter was 218 us (1M device-scope atomics
// on 1024 hot addresses + 3x scattered 4B stores, 94 MB write amplification).
// Replaced with: hist -> per-bucket column scan -> base scan -> LDS-cursor
// scatter writing ONE packed 8B record per element. Zero global atomics.
// Compute kernel (user-side 256KB-window locality) unchanged in structure.

#define NBUCKET 1024
#define BSHIFT  10          // bucket = user >> 10 (1024 rows = 256 KB window)
#define NBLK    256         // chunks for hist/scatter; colscan scans NBLK values
#define PMASK   0x1FFFFFu   // 21-bit fields in packed record

// ---------------- K1: per-chunk histogram ----------------
__global__ __launch_bounds__(256) void mf_hist(const int* __restrict__ user,
                                               int batch, int chunk,
                                               int* __restrict__ cnt)
{
    __shared__ int lc[NBUCKET];
    for (int i = threadIdx.x; i < NBUCKET; i += 256) lc[i] = 0;
    __syncthreads();
    const int beg = blockIdx.x * chunk;
    const int end = min(beg + chunk, batch);
    for (int i = beg + threadIdx.x; i < end; i += 256)
        atomicAdd(&lc[user[i] >> BSHIFT], 1);   // LDS-only atomics
    __syncthreads();
    int* row = cnt + (size_t)blockIdx.x * NBUCKET;
    for (int i = threadIdx.x; i < NBUCKET; i += 256) row[i] = lc[i];
}

// ---------------- K2: per-bucket exclusive scan over blocks ----------------
// grid = NBUCKET blocks, 256 threads (one per hist block). In-place:
// cnt[blk][b] becomes the within-bucket offset of block blk's elements.
__global__ __launch_bounds__(256) void mf_colscan(int* __restrict__ cnt,
                                                  int* __restrict__ total)
{
    const int b    = blockIdx.x;
    const int t    = threadIdx.x;
    const int lane = t & 63;
    const int wid  = t >> 6;

    const int v = cnt[(size_t)t * NBUCKET + b];
    int x = v;
    #pragma unroll
    for (int off = 1; off < 64; off <<= 1) {
        const int y = __shfl_up(x, off, 64);
        if (lane >= off) x += y;
    }
    __shared__ int wsum[4], wpre[4];
    if (lane == 63) wsum[wid] = x;
    __syncthreads();
    if (t == 0) {
        int s = 0;
        #pragma unroll
        for (int w = 0; w < 4; ++w) { wpre[w] = s; s += wsum[w]; }
    }
    __syncthreads();
    const int excl = x - v + wpre[wid];
    cnt[(size_t)t * NBUCKET + b] = excl;
    if (t == 255) total[b] = excl + v;
}

// ---------------- K3: scan bucket totals -> bucket bases ----------------
__global__ __launch_bounds__(1024) void mf_scanbase(const int* __restrict__ total,
                                                    int* __restrict__ base)
{
    const int t    = threadIdx.x;
    const int lane = t & 63;
    const int wid  = t >> 6;

    const int v = total[t];
    int x = v;
    #pragma unroll
    for (int off = 1; off < 64; off <<= 1) {
        const int y = __shfl_up(x, off, 64);
        if (lane >= off) x += y;
    }
    __shared__ int wsum[16], wpre[16];
    if (lane == 63) wsum[wid] = x;
    __syncthreads();
    if (t == 0) {
        int s = 0;
        #pragma unroll
        for (int w = 0; w < 16; ++w) { wpre[w] = s; s += wsum[w]; }
    }
    __syncthreads();
    const int excl = x - v + wpre[wid];
    base[t] = excl;
    if (t == NBUCKET - 1) base[NBUCKET] = excl + v;
}

// ---------------- K4: scatter into packed 8B records, LDS cursors ----------------
__global__ __launch_bounds__(256) void mf_scatter(const int* __restrict__ user,
                                                  const int* __restrict__ item,
                                                  int batch, int chunk,
                                                  const int* __restrict__ cnt,
                                                  const int* __restrict__ base,
                                                  unsigned long long* __restrict__ rec)
{
    __shared__ int cur[NBUCKET];
    const int* row = cnt + (size_t)blockIdx.x * NBUCKET;
    for (int i = threadIdx.x; i < NBUCKET; i += 256)
        cur[i] = base[i] + row[i];             // absolute start for this block
    __syncthreads();

    const int beg = blockIdx.x * chunk;
    const int end = min(beg + chunk, batch);
    for (int i = beg + threadIdx.x; i < end; i += 256) {
        const unsigned u  = (unsigned)user[i];
        const unsigned it = (unsigned)item[i];
        const int slot = atomicAdd(&cur[u >> BSHIFT], 1);   // LDS-only atomic
        rec[slot] = (unsigned long long)u
                  | ((unsigned long long)it << 21)
                  | ((unsigned long long)(unsigned)i << 42);
    }
}

// ---------------- K5: per-bucket compute ----------------
// 16 lanes per row, 4 rows per thread. All user gathers of a block land in
// one 256 KB window of user_weight (DRAM row + L2 locality, dup rows = hits).
__global__ __launch_bounds__(256) void mf_compute(
    const unsigned long long* __restrict__ rec,
    const int*   __restrict__ base,
    const float* __restrict__ user_weight,
    const float* __restrict__ item_weight,
    const float* __restrict__ user_bias,
    const float* __restrict__ item_bias,
    const float* __restrict__ bias,
    float*       __restrict__ out)
{
    const int start = base[blockIdx.x];
    const int end   = base[blockIdx.x + 1];
    if (start >= end) return;

    const int lane16 = threadIdx.x & 15;
    const int grp    = threadIdx.x >> 4;
    const float b0   = bias[0];

    for (int bse = start; bse < end; bse += 64) {
        int u[4], it[4], pos[4];
        bool ok[4];
        #pragma unroll
        for (int k = 0; k < 4; ++k) {
            const int r  = bse + grp + k * 16;
            ok[k]        = r < end;
            const int rr = ok[k] ? r : start;
            const unsigned long long rv = rec[rr];
            u[k]   = (int)(rv & PMASK);
            it[k]  = (int)((rv >> 21) & PMASK);
            pos[k] = (int)(rv >> 42);
        }

        float4 uw[4], iw[4];
        #pragma unroll
        for (int k = 0; k < 4; ++k) {
            uw[k] = ((const float4*)(user_weight + (size_t)u[k]  * 64))[lane16];
            iw[k] = ((const float4*)(item_weight + (size_t)it[k] * 64))[lane16];
        }

        float ub[4], ib[4];
        #pragma unroll
        for (int k = 0; k < 4; ++k) {
            ub[k] = user_bias[u[k]];
            ib[k] = item_bias[it[k]];
        }

        float s[4];
        #pragma unroll
        for (int k = 0; k < 4; ++k) {
            s[k] = (uw[k].x + ub[k]) * (iw[k].x + ib[k])
                 + (uw[k].y + ub[k]) * (iw[k].y + ib[k])
                 + (uw[k].z + ub[k]) * (iw[k].z + ib[k])
                 + (uw[k].w + ub[k]) * (iw[k].w + ib[k]);
        }

        #pragma unroll
        for (int off = 8; off >= 1; off >>= 1) {
            #pragma unroll
            for (int k = 0; k < 4; ++k) s[k] += __shfl_xor(s[k], off, 16);
        }

        if (lane16 == 0) {
            #pragma unroll
            for (int k = 0; k < 4; ++k)
                if (ok[k]) out[pos[k]] = s[k] + b0;
        }
    }
}

// ---------------- fallback: proven direct kernel (~503 us) ----------------
__global__ __launch_bounds__(256) void MF_73856257622285_kernel(
    const int*   __restrict__ user,
    const int*   __restrict__ item,
    const float* __restrict__ user_weight,
    const float* __restrict__ item_weight,
    const float* __restrict__ user_bias,
    const float* __restrict__ item_bias,
    const float* __restrict__ bias,
    float*       __restrict__ out,
    int batch)
{
    const int lane16 = threadIdx.x & 15;
    const int grp    = threadIdx.x >> 4;
    const int row0   = blockIdx.x * 64 + grp;

    int u[4], it[4];
    bool ok[4];
    #pragma unroll
    for (int k = 0; k < 4; ++k) {
        const int r = row0 + k * 16;
        ok[k] = r < batch;
        u[k]  = ok[k] ? user[r] : 0;
        it[k] = ok[k] ? item[r] : 0;
    }

    float4 uw[4], iw[4];
    #pragma unroll
    for (int k = 0; k < 4; ++k) {
        uw[k] = ((const float4*)(user_weight + (size_t)u[k]  * 64))[lane16];
        iw[k] = ((const float4*)(item_weight + (size_t)it[k] * 64))[lane16];
    }

    float ub[4], ib[4];
    #pragma unroll
    for (int k = 0; k < 4; ++k) {
        ub[k] = user_bias[u[k]];
        ib[k] = item_bias[it[k]];
    }

    const float b0 = bias[0];

    float s[4];
    #pragma unroll
    for (int k = 0; k < 4; ++k) {
        s[k] = (uw[k].x + ub[k]) * (iw[k].x + ib[k])
             + (uw[k].y + ub[k]) * (iw[k].y + ib[k])
             + (uw[k].z + ub[k]) * (iw[k].z + ib[k])
             + (uw[k].w + ub[k]) * (iw[k].w + ib[k]);
    }

    #pragma unroll
    for (int off = 8; off >= 1; off >>= 1) {
        #pragma unroll
        for (int k = 0; k < 4; ++k) s[k] += __shfl_xor(s[k], off, 16);
    }

    if (lane16 == 0) {
        #pragma unroll
        for (int k = 0; k < 4; ++k) {
            if (ok[k]) __builtin_nontemporal_store(s[k] + b0, &out[row0 + k * 16]);
        }
    }
}

extern "C" void kernel_launch(void* const* d_in, const int* in_sizes, int n_in,
                              void* d_out, int out_size, void* d_ws, size_t ws_size,
                              hipStream_t stream)
{
    (void)n_in; (void)out_size;

    const int*   user        = (const int*)  d_in[0];
    const int*   item        = (const int*)  d_in[1];
    // d_in[2] = target (unused in forward)
    const float* user_weight = (const float*)d_in[3];
    const float* item_weight = (const float*)d_in[4];
    const float* user_bias   = (const float*)d_in[5];
    const float* item_bias   = (const float*)d_in[6];
    const float* bias        = (const float*)d_in[7];
    float*       out         = (float*)d_out;

    const int batch = in_sizes[0];
    if (batch <= 0) return;

    // Workspace: rec[batch] (8B) | cnt[NBLK][NBUCKET] | total[NBUCKET] | base[NBUCKET+1]
    const size_t need = (size_t)batch * 8
                      + (size_t)NBLK * NBUCKET * 4
                      + (size_t)NBUCKET * 4
                      + (size_t)(NBUCKET + 1) * 4;

    const bool packable = batch <= (1 << 21);   // 21-bit pos field

    if (d_ws != nullptr && ws_size >= need && packable) {
        unsigned long long* rec = (unsigned long long*)d_ws;
        int* cnt   = (int*)(rec + batch);
        int* total = cnt + (size_t)NBLK * NBUCKET;
        int* base  = total + NBUCKET;

        const int chunk = (batch + NBLK - 1) / NBLK;

        mf_hist    <<<NBLK,    256,  0, stream>>>(user, batch, chunk, cnt);
        mf_colscan <<<NBUCKET, 256,  0, stream>>>(cnt, total);
        mf_scanbase<<<1,       1024, 0, stream>>>(total, base);
        mf_scatter <<<NBLK,    256,  0, stream>>>(user, item, batch, chunk,
                                                  cnt, base, rec);
        mf_compute <<<NBUCKET, 256,  0, stream>>>(rec, base,
                                                  user_weight, item_weight,
                                                  user_bias, item_bias, bias, out);
    } else {
        const int threads = 256;
        const int rows_per_block = 64;
        const int blocks = (batch + rows_per_block - 1) / rows_per_block;
        MF_73856257622285_kernel<<<blocks, threads, 0, stream>>>(
            user, item, user_weight, item_weight, user_bias, item_bias, bias,
            out, batch);
    }
}